// Round 2
// baseline (151.573 us; speedup 1.0000x reference)
//
#include <hip/hip_runtime.h>
#include <hip/hip_bf16.h>

#define C_   512
#define HS   128
#define NN   10368   // 18*24*24 ; = 324 k-steps of 32

typedef __bf16 bf16x8 __attribute__((ext_vector_type(8)));
typedef float  f32x4  __attribute__((ext_vector_type(4)));

// ---------------------------------------------------------------------------
// K1 (fused prep): blocks [0,1296): cast features fp32 [C][N] -> xb bf16 [C][N]
//   and xbT bf16 [N][C] via 64x64 LDS tile (stride 65, conflict-free).
// blocks [1296,1360): cast Wi/Wj fp32 -> bf16 (vectorized, 8 elem/thread).
// ---------------------------------------------------------------------------
__global__ void k_prep_transpose(const float* __restrict__ x,
                                 const float* __restrict__ Wi,
                                 const float* __restrict__ Wj,
                                 __bf16* __restrict__ xb,
                                 __bf16* __restrict__ xbT,
                                 __bf16* __restrict__ Wib,
                                 __bf16* __restrict__ Wjb) {
    const int b = blockIdx.x;
    const int t = threadIdx.x;
    if (b < 1296) {
        __shared__ float tile[64][65];
        const int bc = b & 7;           // c block of 64
        const int bn = b >> 3;          // n block of 64
        const int tr = t >> 6;          // 0..3
        const int tn = t & 63;
        const int c0 = bc * 64, n0 = bn * 64;
        for (int i = 0; i < 16; i++) {
            int c = tr + i * 4;
            float v = x[(size_t)(c0 + c) * NN + n0 + tn];
            xb[(size_t)(c0 + c) * NN + n0 + tn] = (__bf16)v;
            tile[c][tn] = v;
        }
        __syncthreads();
        for (int i = 0; i < 16; i++) {
            int n = tr + i * 4;
            xbT[(size_t)(n0 + n) * C_ + c0 + tn] = (__bf16)tile[tn][n];
        }
    } else {
        const int b2 = b - 1296;        // 0..63
        const float* src = (b2 < 32) ? Wi : Wj;
        __bf16* dst      = (b2 < 32) ? Wib : Wjb;
        const int off = (b2 & 31) * 2048 + t * 8;
        float4 v0 = *(const float4*)(src + off);
        float4 v1 = *(const float4*)(src + off + 4);
        __bf16 o[8];
        o[0] = (__bf16)v0.x; o[1] = (__bf16)v0.y; o[2] = (__bf16)v0.z; o[3] = (__bf16)v0.w;
        o[4] = (__bf16)v1.x; o[5] = (__bf16)v1.y; o[6] = (__bf16)v1.z; o[7] = (__bf16)v1.w;
        *(bf16x8*)(dst + off) = *(bf16x8*)o;
    }
}

// ---------------------------------------------------------------------------
// K2 (fused G1+G2): 1296 waves.
//   waves [0,648):   fj[h][n]   = sum_c Wj[h][c]*x[c][n] + bj[h]
//   waves [648,1296) finm[n][h] = sum_c x[c][n]*Wi[h][c] + bi[h]
// All fragment loads are contiguous-16B direct global loads (L2/L3-resident).
// ---------------------------------------------------------------------------
__global__ void k_gemm12(const __bf16* __restrict__ xbT,
                         const __bf16* __restrict__ Wib, const __bf16* __restrict__ Wjb,
                         const float* __restrict__ bi, const float* __restrict__ bj,
                         __bf16* __restrict__ fj, __bf16* __restrict__ finm) {
    const int w    = blockIdx.x * 4 + (threadIdx.x >> 6);
    const int lane = threadIdx.x & 63;
    const int l16  = lane & 15;
    const int q    = lane >> 4;
    if (w < 648) {
        const int h0 = (w & 3) * 32, n0 = (w >> 2) * 64;
        f32x4 acc[2][4] = {};
        for (int k = 0; k < 512; k += 32) {
            bf16x8 a[2], b[4];
            #pragma unroll
            for (int i = 0; i < 2; i++)
                a[i] = *(const bf16x8*)(Wjb + (h0 + 16 * i + l16) * 512 + k + q * 8);
            #pragma unroll
            for (int t = 0; t < 4; t++)
                b[t] = *(const bf16x8*)(xbT + (size_t)(n0 + 16 * t + l16) * 512 + k + q * 8);
            #pragma unroll
            for (int i = 0; i < 2; i++)
                #pragma unroll
                for (int t = 0; t < 4; t++)
                    acc[i][t] = __builtin_amdgcn_mfma_f32_16x16x32_bf16(a[i], b[t], acc[i][t], 0, 0, 0);
        }
        #pragma unroll
        for (int i = 0; i < 2; i++)
            #pragma unroll
            for (int t = 0; t < 4; t++)
                #pragma unroll
                for (int r = 0; r < 4; r++) {
                    int h = h0 + 16 * i + q * 4 + r;
                    int n = n0 + 16 * t + l16;
                    fj[(size_t)h * NN + n] = (__bf16)(acc[i][t][r] + bj[h]);
                }
    } else {
        const int w2 = w - 648;
        const int n0 = (w2 >> 2) * 64, h0 = (w2 & 3) * 32;
        f32x4 acc[4][2] = {};
        for (int k = 0; k < 512; k += 32) {
            bf16x8 a[4], b[2];
            #pragma unroll
            for (int i = 0; i < 4; i++)
                a[i] = *(const bf16x8*)(xbT + (size_t)(n0 + 16 * i + l16) * 512 + k + q * 8);
            #pragma unroll
            for (int t = 0; t < 2; t++)
                b[t] = *(const bf16x8*)(Wib + (h0 + 16 * t + l16) * 512 + k + q * 8);
            #pragma unroll
            for (int i = 0; i < 4; i++)
                #pragma unroll
                for (int t = 0; t < 2; t++)
                    acc[i][t] = __builtin_amdgcn_mfma_f32_16x16x32_bf16(a[i], b[t], acc[i][t], 0, 0, 0);
        }
        #pragma unroll
        for (int i = 0; i < 4; i++)
            #pragma unroll
            for (int t = 0; t < 2; t++)
                #pragma unroll
                for (int r = 0; r < 4; r++) {
                    int n = n0 + 16 * i + q * 4 + r;
                    int h = h0 + 16 * t + l16;
                    finm[(size_t)n * HS + h] = (__bf16)(acc[i][t][r] + bi[h]);
                }
    }
}

// ---------------------------------------------------------------------------
// K3 (G3, no atomics): MT[c][h] = sum_n xb[c][n] * fj[h][n]
//   256 blocks = 64 tiles (32c x 32h) x 4 chunk-groups. The 4 waves of a
//   block cover the SAME tile over 4 different K-chunks (16 chunks total,
//   ~20 k-steps each), LDS-reduce across waves, write fp32 partial Mp[g].
// ---------------------------------------------------------------------------
__global__ void k_gemm3p(const __bf16* __restrict__ xb, const __bf16* __restrict__ fj,
                         float* __restrict__ Mp) {
    __shared__ float red[3][64][16];
    const int b    = blockIdx.x;             // 0..255
    const int v    = threadIdx.x >> 6;       // wave 0..3
    const int lane = threadIdx.x & 63;
    const int l16  = lane & 15;
    const int q    = lane >> 4;
    const int tile = b & 63, g = b >> 6;     // 64 tiles x 4 groups
    const int c0 = (tile >> 2) * 32, h0 = (tile & 3) * 32;
    const int chunk = g * 4 + v;             // 0..15
    const int s0 = (chunk * 324) >> 4;
    const int s1 = ((chunk + 1) * 324) >> 4;
    f32x4 acc[2][2] = {};
    for (int s = s0; s < s1; s++) {
        int k = s * 32;
        bf16x8 a[2], bb[2];
        #pragma unroll
        for (int i = 0; i < 2; i++)
            a[i] = *(const bf16x8*)(xb + (size_t)(c0 + 16 * i + l16) * NN + k + q * 8);
        #pragma unroll
        for (int t = 0; t < 2; t++)
            bb[t] = *(const bf16x8*)(fj + (size_t)(h0 + 16 * t + l16) * NN + k + q * 8);
        #pragma unroll
        for (int i = 0; i < 2; i++)
            #pragma unroll
            for (int t = 0; t < 2; t++)
                acc[i][t] = __builtin_amdgcn_mfma_f32_16x16x32_bf16(a[i], bb[t], acc[i][t], 0, 0, 0);
    }
    if (v > 0) {
        #pragma unroll
        for (int i = 0; i < 2; i++)
            #pragma unroll
            for (int t = 0; t < 2; t++)
                #pragma unroll
                for (int r = 0; r < 4; r++)
                    red[v - 1][lane][i * 8 + t * 4 + r] = acc[i][t][r];
    }
    __syncthreads();
    if (v == 0) {
        float* dst = Mp + g * (C_ * HS);
        #pragma unroll
        for (int i = 0; i < 2; i++)
            #pragma unroll
            for (int t = 0; t < 2; t++)
                #pragma unroll
                for (int r = 0; r < 4; r++) {
                    int j = i * 8 + t * 4 + r;
                    float s = acc[i][t][r] + red[0][lane][j] + red[1][lane][j] + red[2][lane][j];
                    int c = c0 + 16 * i + q * 4 + r;
                    int h = h0 + 16 * t + l16;
                    dst[c * HS + h] = s;
                }
    }
}

// ---------------------------------------------------------------------------
// K4 (G4 + scale + residual): out[c][n] = feat[c][n] + scale*sum_h M[c][h]*finm[n][h]
//   A-fragments built in-register: sum 4 fp32 partials of M, cvt to bf16.
//   scale = agg/N applied post-MFMA (mathematically identical, kills k_scale).
// ---------------------------------------------------------------------------
__global__ void k_gemm4(const float* __restrict__ Mp, const __bf16* __restrict__ finm,
                        const float* __restrict__ feat, const float* __restrict__ agg,
                        float* __restrict__ out) {
    const int w    = blockIdx.x * 4 + (threadIdx.x >> 6);   // 0..2591
    const int lane = threadIdx.x & 63;
    const int l16  = lane & 15;
    const int q    = lane >> 4;
    const int c0 = (w & 15) * 32, n0 = (w >> 4) * 64;
    const float scale = agg[0] * (1.0f / (float)NN);
    f32x4 acc[2][4] = {};
    for (int k = 0; k < 128; k += 32) {
        bf16x8 a[2], b[4];
        #pragma unroll
        for (int i = 0; i < 2; i++) {
            const int base = (c0 + 16 * i + l16) * HS + k + q * 8;
            f32x4 s0 = *(const f32x4*)(Mp + base);
            f32x4 s1 = *(const f32x4*)(Mp + base + 4);
            #pragma unroll
            for (int g = 1; g < 4; g++) {
                s0 += *(const f32x4*)(Mp + g * (C_ * HS) + base);
                s1 += *(const f32x4*)(Mp + g * (C_ * HS) + base + 4);
            }
            #pragma unroll
            for (int j = 0; j < 4; j++) {
                a[i][j]     = (__bf16)s0[j];
                a[i][4 + j] = (__bf16)s1[j];
            }
        }
        #pragma unroll
        for (int t = 0; t < 4; t++)
            b[t] = *(const bf16x8*)(finm + (size_t)(n0 + 16 * t + l16) * HS + k + q * 8);
        #pragma unroll
        for (int i = 0; i < 2; i++)
            #pragma unroll
            for (int t = 0; t < 4; t++)
                acc[i][t] = __builtin_amdgcn_mfma_f32_16x16x32_bf16(a[i], b[t], acc[i][t], 0, 0, 0);
    }
    #pragma unroll
    for (int i = 0; i < 2; i++)
        #pragma unroll
        for (int t = 0; t < 4; t++)
            #pragma unroll
            for (int r = 0; r < 4; r++) {
                int c = c0 + 16 * i + q * 4 + r;
                int n = n0 + 16 * t + l16;
                size_t idx = (size_t)c * NN + n;
                out[idx] = feat[idx] + scale * acc[i][t][r];
            }
}

// ---------------------------------------------------------------------------
// Workspace layout (bytes, 16B-aligned):
//   xb   @ 0          : 10,616,832
//   xbT  @ 10,616,832 : 10,616,832
//   Wib  @ 21,233,664 : 131,072
//   Wjb  @ 21,364,736 : 131,072
//   fj   @ 21,495,808 : 2,654,208
//   finm @ 24,150,016 : 2,654,208
//   Mp   @ 26,804,224 : 4 x 512*128*4 = 1,048,576   total ~27.9 MB
// ---------------------------------------------------------------------------
extern "C" void kernel_launch(void* const* d_in, const int* in_sizes, int n_in,
                              void* d_out, int out_size, void* d_ws, size_t ws_size,
                              hipStream_t stream) {
    const float* feat = (const float*)d_in[0];
    const float* Wi   = (const float*)d_in[1];
    const float* bi   = (const float*)d_in[2];
    const float* Wj   = (const float*)d_in[3];
    const float* bj   = (const float*)d_in[4];
    const float* agg  = (const float*)d_in[5];
    float* out = (float*)d_out;

    char* ws = (char*)d_ws;
    __bf16* xb   = (__bf16*)(ws);
    __bf16* xbT  = (__bf16*)(ws + 10616832);
    __bf16* Wib  = (__bf16*)(ws + 21233664);
    __bf16* Wjb  = (__bf16*)(ws + 21364736);
    __bf16* fj   = (__bf16*)(ws + 21495808);
    __bf16* finm = (__bf16*)(ws + 24150016);
    float*  Mp   = (float*) (ws + 26804224);

    k_prep_transpose<<<1360, 256, 0, stream>>>(feat, Wi, Wj, xb, xbT, Wib, Wjb);
    k_gemm12<<<324, 256, 0, stream>>>(xbT, Wib, Wjb, bi, bj, fj, finm);
    k_gemm3p<<<256, 256, 0, stream>>>(xb, fj, Mp);
    k_gemm4<<<648, 256, 0, stream>>>(Mp, finm, feat, agg, out);
}